// Round 16
// baseline (76.833 us; speedup 1.0000x reference)
//
#include <hip/hip_runtime.h>

// B=8192, J=17, F=128. f32 in/out.
// ws layout (float index):
//   [0, 32768)        : 128 slots x (128 sum + 128 sumsq) BN partials (memset 0 per launch)
//   [32768, 33024)    : stats: scale[128], shift[128]
//   [33024, 33364)    : off_sym padded [17][20] (rows 16B-aligned; symmetric; pads zeroed)
//   [33364, 33381)    : diag[17]
//   [33408, 49792)    : W^T bf16 [256 cols][128 k] = 32768 shorts = 16384 floats (64KB)
//   [49792, ...)      : bf16 pre-BN activations [139264*128] (35.7MB) if ws_size allows
// Lessons: R5 no 64-reg cap; R6 keep A in LDS (clamp trick OK); R7 no &vec[i];
// R8/R10/R12 NEVER feed raw MFMA acc into inline asm -> pure-C f2bf for acc packing
// (R8's real bug was pk2-on-acc, NOT the Mlds float4 staging); R10 bisect-don't-bundle;
// R14 split costs +142MB traffic -> stay fused. R16 = R15 + M staged in LDS
// (kills 17 late global loads/thread in the mixing tail).

#define NSLOT      128
#define OFF_PART   0
#define OFF_STATS  32768
#define OFF_OFFSYM 33024
#define OFF_DIAG   33364
#define OFF_WBT    33408
#define OFF_PRE    49792
#define PRE_SHORTS (139264ull * 128ull)

typedef __attribute__((ext_vector_type(8))) short bf16x8;
typedef __attribute__((ext_vector_type(4))) short bf16x4;
typedef __attribute__((ext_vector_type(4))) float f32x4;
typedef union { unsigned u[2]; bf16x4 v; } pk4U;

__device__ __forceinline__ short f2bf(float f) {
    unsigned u = __float_as_uint(f);
    u += 0x7FFFu + ((u >> 16) & 1u);   // round-to-nearest-even
    return (short)(u >> 16);
}
__device__ __forceinline__ float bf2f(short h) {
    return __uint_as_float(((unsigned)(unsigned short)h) << 16);
}
__device__ __forceinline__ float bflo(int p) {
    return __uint_as_float(((unsigned)p) << 16);
}
__device__ __forceinline__ float bfhi(int p) {
    return __uint_as_float(((unsigned)p) & 0xFFFF0000u);
}
// one v_cvt_pk_bf16_f32: low16 = bf16(a), high16 = bf16(b), RNE.
// ONLY for VALU-produced values (never raw MFMA acc -- R8/R10/R12 failures).
__device__ __forceinline__ unsigned pk2(float a, float b) {
    unsigned r;
    asm("v_cvt_pk_bf16_f32 %0, %1, %2" : "=v"(r) : "v"(a), "v"(b));
    return r;
}

// ---------------- prep: 17 blocks. blk0: adjacency; blk1..16: W^T bf16 ----------------
__global__ __launch_bounds__(256) void prep_kernel(
    const float* __restrict__ W, const float* __restrict__ adj,
    const float* __restrict__ adj2, float* __restrict__ wsf)
{
    const int t = threadIdx.x, b = blockIdx.x;
    if (b == 0) {
        for (int e = t; e < 340; e += 256) {     // padded [17][20], pads -> 0
            int i = e / 20, j = e % 20;
            float v = 0.f;
            if (j < 17) {
                v = 0.5f * (adj[i*17+j] + adj2[i*17+j] + adj[j*17+i] + adj2[j*17+i]);
                if (i == j) { wsf[OFF_DIAG + i] = v; v = 0.f; }
            }
            wsf[OFF_OFFSYM + e] = v;
        }
        return;
    }
    short* wbt = (short*)(wsf + OFF_WBT);
    const int col = (b - 1) * 16 + (t >> 4);
    const int k0  = (t & 15) * 8;
    const int sel = col >> 7, colp = col & 127;
    const float* src = W + sel * 16384 + colp;   // W[sel][k][colp]
    bf16x8 p;
    #pragma unroll
    for (int e = 0; e < 8; ++e) p[e] = f2bf(src[(k0 + e) * 128]);
    *(bf16x8*)(wbt + col * 128 + k0) = p;
}

// ---------------- conv: 68 rows/block; wave-independent tail (R15) + Mlds ----------
// LDS union U (34816B): phase1 A-tile short[68][136]; phase2 per-wave hh slices
// int[8][68][16]. Mlds[17][128] f32 (8704B) staged once; offs[17][20]; dlds.
// Exactly 2 barriers. Epilogue packs acc via pure-C f2bf.
__global__ __launch_bounds__(512, 2) void conv_kernel(
    const float* __restrict__ x, const float* __restrict__ M,
    const float* __restrict__ bias, float* ws, short* __restrict__ pre)
{
    __shared__ int U[8704];
    __shared__ __align__(16) float Mlds[2176];
    __shared__ __align__(16) float offs[340];
    __shared__ float dlds[20];
    short (*A)[136] = (short(*)[136])U;     // phase 1 only

    const int tid = threadIdx.x;
    const int w = tid >> 6, l = tid & 63, c = l & 15, g = l >> 4;
    const int col = w * 16 + c;

    const float bv = bias[col];              // early; used in mixing

    for (int e = tid; e < 340; e += 512) offs[e] = ws[OFF_OFFSYM + e];
    if (tid < 17) dlds[tid] = ws[OFF_DIAG + tid];
    {   // stage M[17][128] -> LDS, 544 float4 (16B-aligned: base align 16, off e*16)
        const float4* m4 = (const float4*)M;
        for (int e = tid; e < 544; e += 512)
            *(float4*)&Mlds[e * 4] = m4[e];
    }

    // ---- stage x[blk*68 .. +68) f32 -> bf16 LDS (2176 float4) ----
    const float4* xsrc = (const float4*)(x + (size_t)blockIdx.x * (68 * 128));
    #pragma unroll
    for (int it = 0; it < 5; ++it) {
        int f = tid + it * 512;
        if (f < 2176) {
            float4 v = xsrc[f];
            int r = f >> 5, k0 = (f & 31) << 2;
            pk4U p;
            p.u[0] = pk2(v.x, v.y);
            p.u[1] = pk2(v.z, v.w);
            *(bf16x4*)&A[r][k0] = p.v;
        }
    }
    __syncthreads();

    // ---- K-loop: wave w owns col for h0 (col) and h1 (col+128) ----
    const short* wbt = (const short*)(ws + OFF_WBT);
    f32x4 acc0[5], acc1[5];
    #pragma unroll
    for (int mt = 0; mt < 5; ++mt) {
        acc0[mt] = (f32x4){0.f, 0.f, 0.f, 0.f};
        acc1[mt] = (f32x4){0.f, 0.f, 0.f, 0.f};
    }
    #pragma unroll
    for (int ks = 0; ks < 4; ++ks) {
        bf16x8 b0 = *(const bf16x8*)(wbt + col * 128 + ks * 32 + g * 8);
        bf16x8 b1 = *(const bf16x8*)(wbt + (col + 128) * 128 + ks * 32 + g * 8);
        #pragma unroll
        for (int mt = 0; mt < 5; ++mt) {
            // mt=4 frag rows 68..79 don't exist: clamp (R6-proven); garbage
            // D-rows >=68 are discarded by the row<68 guard below.
            const int arow = (mt < 4) ? (mt * 16 + c) : (64 + (c & 3));
            bf16x8 af = *(const bf16x8*)&A[arow][ks * 32 + g * 8];
            acc0[mt] = __builtin_amdgcn_mfma_f32_16x16x32_bf16(af, b0, acc0[mt], 0, 0, 0);
            acc1[mt] = __builtin_amdgcn_mfma_f32_16x16x32_bf16(af, b1, acc1[mt], 0, 0, 0);
        }
    }
    __syncthreads();   // all waves' A reads done; U becomes per-wave hh slices

    // ---- epilogue (per-wave): pack acc via pure-C f2bf into own slice ----
    int* hw = U + w * 1088;                 // [68][16] ints
    #pragma unroll
    for (int mt = 0; mt < 5; ++mt) {
        #pragma unroll
        for (int r = 0; r < 4; ++r) {
            int row = mt * 16 + g * 4 + r;
            if (row < 68) {
                unsigned pk = ((unsigned)(unsigned short)f2bf(acc0[mt][r])) |
                              (((unsigned)(unsigned short)f2bf(acc1[mt][r])) << 16);
                hw[row * 16 + c] = (int)pk;
            }
        }
    }

    // ---- mixing (per-wave): lane (c,g) -> batch g, col; all inputs from LDS ----
    int pj[17]; float mcol[17];
    #pragma unroll
    for (int i = 0; i < 17; ++i) {
        pj[i]   = hw[(g * 17 + i) * 16 + c];
        mcol[i] = Mlds[i * 128 + col];      // 16 banks + 4-way broadcast: conflict-free
    }

    float vout[17];
    #pragma unroll
    for (int i = 0; i < 17; ++i)
        vout[i] = fmaf(dlds[i] * mcol[i], bflo(pj[i]), bv);   // diag*M*h0 + bias
    #pragma unroll
    for (int j = 0; j < 17; ++j) {
        float hv = mcol[j] * bfhi(pj[j]);                      // M*h1
        const f32x4* orow = (const f32x4*)&offs[j * 20];       // symmetric rows
        f32x4 o0 = orow[0], o1 = orow[1], o2 = orow[2], o3 = orow[3];
        float oz = offs[j * 20 + 16];
        vout[0]  = fmaf(o0.x, hv, vout[0]);
        vout[1]  = fmaf(o0.y, hv, vout[1]);
        vout[2]  = fmaf(o0.z, hv, vout[2]);
        vout[3]  = fmaf(o0.w, hv, vout[3]);
        vout[4]  = fmaf(o1.x, hv, vout[4]);
        vout[5]  = fmaf(o1.y, hv, vout[5]);
        vout[6]  = fmaf(o1.z, hv, vout[6]);
        vout[7]  = fmaf(o1.w, hv, vout[7]);
        vout[8]  = fmaf(o2.x, hv, vout[8]);
        vout[9]  = fmaf(o2.y, hv, vout[9]);
        vout[10] = fmaf(o2.z, hv, vout[10]);
        vout[11] = fmaf(o2.w, hv, vout[11]);
        vout[12] = fmaf(o3.x, hv, vout[12]);
        vout[13] = fmaf(o3.y, hv, vout[13]);
        vout[14] = fmaf(o3.z, hv, vout[14]);
        vout[15] = fmaf(o3.w, hv, vout[15]);
        vout[16] = fmaf(oz,   hv, vout[16]);
    }

    float s = 0.f, s2 = 0.f;
    const size_t gbase = ((size_t)blockIdx.x * 68 + g * 17) * 128 + col;
    #pragma unroll
    for (int i = 0; i < 17; ++i) {
        float v = vout[i];
        pre[gbase + (size_t)i * 128] = (short)pk2(v, v);   // v is VALU-produced: OK
        s += v; s2 = fmaf(v, v, s2);
    }

    // ---- stats: butterfly over g (lane bits 4,5), 16 lane-atomics/wave ----
    s  += __shfl_xor(s, 16);  s  += __shfl_xor(s, 32);
    s2 += __shfl_xor(s2, 16); s2 += __shfl_xor(s2, 32);
    if (l < 16) {
        float* slot = ws + OFF_PART + ((blockIdx.x & (NSLOT - 1)) << 8);
        atomicAdd(slot + col, s);
        atomicAdd(slot + 128 + col, s2);
    }
}

// ---------------- fallback fused conv (R11-proven, f32 out path) ----------------
__global__ __launch_bounds__(512, 4) void conv_f32_kernel(
    const float* __restrict__ x, const float* __restrict__ M,
    const float* __restrict__ bias, float* ws, float* __restrict__ out)
{
    __shared__ int hhI[68 * 130];
    __shared__ __align__(16) float offs[340];
    short (*A)[136] = (short(*)[136])hhI;
    const int tid = threadIdx.x;
    const int w = tid >> 6, l = tid & 63, c = l & 15, g = l >> 4;
    for (int e = tid; e < 340; e += 512) offs[e] = ws[OFF_OFFSYM + e];
    const float4* xsrc = (const float4*)(x + (size_t)blockIdx.x * (68 * 128));
    #pragma unroll
    for (int it = 0; it < 5; ++it) {
        int f = tid + it * 512;
        if (f < 2176) {
            float4 v = xsrc[f];
            int r = f >> 5, k0 = (f & 31) << 2;
            pk4U p; p.u[0] = pk2(v.x, v.y); p.u[1] = pk2(v.z, v.w);
            *(bf16x4*)&A[r][k0] = p.v;
        }
    }
    if (tid < 408) { bf16x4 z = {0,0,0,0}; ((bf16x4*)&A[68][0])[tid] = z; }
    __syncthreads();
    const short* wbt = (const short*)(ws + OFF_WBT);
    const int col = w * 16 + c;
    f32x4 acc0[5], acc1[5];
    #pragma unroll
    for (int mt = 0; mt < 5; ++mt) {
        acc0[mt] = (f32x4){0.f,0.f,0.f,0.f}; acc1[mt] = (f32x4){0.f,0.f,0.f,0.f};
    }
    #pragma unroll
    for (int ks = 0; ks < 4; ++ks) {
        bf16x8 b0 = *(const bf16x8*)(wbt + col * 128 + ks * 32 + g * 8);
        bf16x8 b1 = *(const bf16x8*)(wbt + (col + 128) * 128 + ks * 32 + g * 8);
        #pragma unroll
        for (int mt = 0; mt < 5; ++mt) {
            bf16x8 af = *(const bf16x8*)&A[mt * 16 + c][ks * 32 + g * 8];
            acc0[mt] = __builtin_amdgcn_mfma_f32_16x16x32_bf16(af, b0, acc0[mt], 0, 0, 0);
            acc1[mt] = __builtin_amdgcn_mfma_f32_16x16x32_bf16(af, b1, acc1[mt], 0, 0, 0);
        }
    }
    __syncthreads();
    const float bv = bias[col];
    #pragma unroll
    for (int mt = 0; mt < 5; ++mt) {
        #pragma unroll
        for (int r = 0; r < 4; ++r) {
            int row = mt * 16 + g * 4 + r;
            if (row < 68) {
                int j = row - 17 * ((row * 241) >> 12);
                float m  = M[j * 128 + col];
                float dg = ws[OFF_DIAG + j];
                float lo = fmaf(dg * m, acc0[mt][r], bv);
                float hi = m * acc1[mt][r];
                hhI[row * 130 + col] = (int)pk2(lo, hi);
            }
        }
    }
    __syncthreads();
    const int bb = tid >> 7, o = tid & 127;
    const int rb = bb * 17;
    int pj[17];
    #pragma unroll
    for (int i = 0; i < 17; ++i) pj[i] = hhI[(rb + i) * 130 + o];
    float vout[17];
    #pragma unroll
    for (int q = 0; q < 17; ++q) vout[q] = bflo(pj[q]);
    #pragma unroll
    for (int j = 0; j < 17; ++j) {
        float h1v = bfhi(pj[j]);
        #pragma unroll
        for (int q = 0; q < 17; ++q) vout[q] = fmaf(offs[j * 20 + q], h1v, vout[q]);
    }
    float s = 0.f, s2 = 0.f;
    const size_t gbase = ((size_t)blockIdx.x * 68 + rb) * 128 + o;
    #pragma unroll
    for (int q = 0; q < 17; ++q) {
        float v = vout[q];
        out[gbase + (size_t)q * 128] = v;
        s += v; s2 = fmaf(v, v, s2);
    }
    float* slot = ws + OFF_PART + ((blockIdx.x & (NSLOT - 1)) << 8);
    atomicAdd(slot + o, s);
    atomicAdd(slot + 128 + o, s2);
}

// ---------------- BN stats reduce ----------------
__global__ __launch_bounds__(256) void bn_reduce_kernel(
    const float* __restrict__ part, const float* __restrict__ gamma,
    const float* __restrict__ beta, float* __restrict__ stats)
{
    const int t = threadIdx.x;             // 0..255
    float s = 0.f;
    #pragma unroll 8
    for (int i = 0; i < NSLOT; ++i) s += part[i * 256 + t];
    __shared__ float tot[256];
    tot[t] = s;
    __syncthreads();
    if (t < 128) {
        const float n = 139264.f;          // 8192*17
        float mean = tot[t] / n;
        float var  = tot[t + 128] / n - mean * mean;
        var = fmaxf(var, 0.f);
        float inv = rsqrtf(var + 1e-5f);
        float sc = gamma[t] * inv;
        stats[t] = sc;
        stats[t + 128] = beta[t] - mean * sc;
    }
}

// ---------------- BN apply + relu: bf16 pre (ws) -> f32 out ----------------
__global__ __launch_bounds__(256) void apply_bf16_kernel(
    const short* __restrict__ pre, const float* __restrict__ stats,
    float* __restrict__ out)
{
    const int tid = blockIdx.x * 256 + threadIdx.x;
    const int c0 = (tid << 3) & 127;       // stride (524288*8) % 128 == 0
    float sc[8], sh[8];
    #pragma unroll
    for (int e = 0; e < 8; ++e) { sc[e] = stats[c0 + e]; sh[e] = stats[128 + c0 + e]; }
    const bf16x8* p8 = (const bf16x8*)pre;
    for (int q = tid; q < 2228224; q += 524288) {
        bf16x8 v = p8[q];
        float4 o0, o1;
        o0.x = fmaxf(fmaf(bf2f(v[0]), sc[0], sh[0]), 0.f);
        o0.y = fmaxf(fmaf(bf2f(v[1]), sc[1], sh[1]), 0.f);
        o0.z = fmaxf(fmaf(bf2f(v[2]), sc[2], sh[2]), 0.f);
        o0.w = fmaxf(fmaf(bf2f(v[3]), sc[3], sh[3]), 0.f);
        o1.x = fmaxf(fmaf(bf2f(v[4]), sc[4], sh[4]), 0.f);
        o1.y = fmaxf(fmaf(bf2f(v[5]), sc[5], sh[5]), 0.f);
        o1.z = fmaxf(fmaf(bf2f(v[6]), sc[6], sh[6]), 0.f);
        o1.w = fmaxf(fmaf(bf2f(v[7]), sc[7], sh[7]), 0.f);
        float4* dst = (float4*)(out + (size_t)q * 8);
        dst[0] = o0; dst[1] = o1;
    }
}

// ---------------- BN apply + relu fallback (in-place f32) ----------------
__global__ __launch_bounds__(256) void apply_kernel(
    float* __restrict__ out, const float* __restrict__ stats, int n4)
{
    const int tid = blockIdx.x * 256 + threadIdx.x;
    const int c0 = (tid << 2) & 127;
    const float sc0 = stats[c0],     sc1 = stats[c0 + 1],
                sc2 = stats[c0 + 2], sc3 = stats[c0 + 3];
    const float sh0 = stats[128 + c0],     sh1 = stats[128 + c0 + 1],
                sh2 = stats[128 + c0 + 2], sh3 = stats[128 + c0 + 3];
    float4* o4 = (float4*)out;
    for (int q = tid; q < n4; q += 2048 * 256) {
        float4 v = o4[q];
        v.x = fmaxf(fmaf(v.x, sc0, sh0), 0.f);
        v.y = fmaxf(fmaf(v.y, sc1, sh1), 0.f);
        v.z = fmaxf(fmaf(v.z, sc2, sh2), 0.f);
        v.w = fmaxf(fmaf(v.w, sc3, sh3), 0.f);
        o4[q] = v;
    }
}

extern "C" void kernel_launch(void* const* d_in, const int* in_sizes, int n_in,
                              void* d_out, int out_size, void* d_ws, size_t ws_size,
                              hipStream_t stream) {
    (void)in_sizes; (void)n_in; (void)out_size;
    const float* x     = (const float*)d_in[0];
    const float* W     = (const float*)d_in[1];
    const float* M     = (const float*)d_in[2];
    const float* adj   = (const float*)d_in[3];
    const float* adj2  = (const float*)d_in[4];
    const float* bias  = (const float*)d_in[5];
    const float* gamma = (const float*)d_in[6];
    const float* beta  = (const float*)d_in[7];
    float* out = (float*)d_out;
    float* wsf = (float*)d_ws;
    short* pre = (short*)(wsf + OFF_PRE);

    const bool big = ws_size >= (size_t)OFF_PRE * 4 + PRE_SHORTS * 2;

    (void)hipMemsetAsync(d_ws, 0, NSLOT * 256 * sizeof(float), stream);   // BN partials
    prep_kernel<<<17, 256, 0, stream>>>(W, adj, adj2, wsf);
    if (big) {
        conv_kernel<<<2048, 512, 0, stream>>>(x, M, bias, wsf, pre);
        bn_reduce_kernel<<<1, 256, 0, stream>>>(wsf + OFF_PART, gamma, beta, wsf + OFF_STATS);
        apply_bf16_kernel<<<2048, 256, 0, stream>>>(pre, wsf + OFF_STATS, out);
    } else {
        conv_f32_kernel<<<2048, 512, 0, stream>>>(x, M, bias, wsf, out);
        bn_reduce_kernel<<<1, 256, 0, stream>>>(wsf + OFF_PART, gamma, beta, wsf + OFF_STATS);
        apply_kernel<<<2048, 256, 0, stream>>>(out, wsf + OFF_STATS, 4456448);
    }
}

// Round 17
// 73.924 us; speedup vs baseline: 1.0393x; 1.0393x over previous
//
#include <hip/hip_runtime.h>

// B=8192, J=17, F=128. f32 in/out.
// ws layout (float index):
//   [0, 32768)        : 128 slots x (128 sum + 128 sumsq) BN partials (memset 0 per launch)
//   [32768, 33024)    : stats: scale[128], shift[128]
//   [33024, 33364)    : off_sym padded [17][20] (rows 16B-aligned; symmetric; pads zeroed)
//   [33364, 33381)    : diag[17]
//   [33408, 49792)    : W^T bf16 [256 cols][128 k] = 32768 shorts = 16384 floats (64KB)
//   [49792, ...)      : bf16 pre-BN activations [139264*128] (35.7MB) if ws_size allows
// Lessons: R5 don't cap regs BELOW need (8+ deficit -> spills); R6 A in LDS, clamp OK;
// R7 no &vec[i]; R8/R10/R12 NEVER feed raw MFMA acc into inline asm (pure-C f2bf);
// R10 bisect-don't-bundle; R14 split costs +142MB -> stay fused.
// R16 freed VGPR 60->44 (M in LDS). R17 = R16 + __launch_bounds__(512,6):
// combined cap 512/6=85 regs vs ~84 live -> 3 blocks/CU instead of 2.

#define NSLOT      128
#define OFF_PART   0
#define OFF_STATS  32768
#define OFF_OFFSYM 33024
#define OFF_DIAG   33364
#define OFF_WBT    33408
#define OFF_PRE    49792
#define PRE_SHORTS (139264ull * 128ull)

typedef __attribute__((ext_vector_type(8))) short bf16x8;
typedef __attribute__((ext_vector_type(4))) short bf16x4;
typedef __attribute__((ext_vector_type(4))) float f32x4;
typedef union { unsigned u[2]; bf16x4 v; } pk4U;

__device__ __forceinline__ short f2bf(float f) {
    unsigned u = __float_as_uint(f);
    u += 0x7FFFu + ((u >> 16) & 1u);   // round-to-nearest-even
    return (short)(u >> 16);
}
__device__ __forceinline__ float bf2f(short h) {
    return __uint_as_float(((unsigned)(unsigned short)h) << 16);
}
__device__ __forceinline__ float bflo(int p) {
    return __uint_as_float(((unsigned)p) << 16);
}
__device__ __forceinline__ float bfhi(int p) {
    return __uint_as_float(((unsigned)p) & 0xFFFF0000u);
}
// one v_cvt_pk_bf16_f32: low16 = bf16(a), high16 = bf16(b), RNE.
// ONLY for VALU-produced values (never raw MFMA acc -- R8/R10/R12 failures).
__device__ __forceinline__ unsigned pk2(float a, float b) {
    unsigned r;
    asm("v_cvt_pk_bf16_f32 %0, %1, %2" : "=v"(r) : "v"(a), "v"(b));
    return r;
}

// ---------------- prep: 17 blocks. blk0: adjacency; blk1..16: W^T bf16 ----------------
__global__ __launch_bounds__(256) void prep_kernel(
    const float* __restrict__ W, const float* __restrict__ adj,
    const float* __restrict__ adj2, float* __restrict__ wsf)
{
    const int t = threadIdx.x, b = blockIdx.x;
    if (b == 0) {
        for (int e = t; e < 340; e += 256) {     // padded [17][20], pads -> 0
            int i = e / 20, j = e % 20;
            float v = 0.f;
            if (j < 17) {
                v = 0.5f * (adj[i*17+j] + adj2[i*17+j] + adj[j*17+i] + adj2[j*17+i]);
                if (i == j) { wsf[OFF_DIAG + i] = v; v = 0.f; }
            }
            wsf[OFF_OFFSYM + e] = v;
        }
        return;
    }
    short* wbt = (short*)(wsf + OFF_WBT);
    const int col = (b - 1) * 16 + (t >> 4);
    const int k0  = (t & 15) * 8;
    const int sel = col >> 7, colp = col & 127;
    const float* src = W + sel * 16384 + colp;   // W[sel][k][colp]
    bf16x8 p;
    #pragma unroll
    for (int e = 0; e < 8; ++e) p[e] = f2bf(src[(k0 + e) * 128]);
    *(bf16x8*)(wbt + col * 128 + k0) = p;
}

// ---------------- conv: 68 rows/block; wave-independent tail + Mlds + reg-cap ----------
// LDS union U (34816B): phase1 A-tile short[68][136]; phase2 per-wave hh slices
// int[8][68][16]. Mlds[17][128] f32 (8704B); offs[17][20]; dlds.
// Exactly 2 barriers. Epilogue packs acc via pure-C f2bf.
// (512,6): combined VGPR+AGPR cap 85 -> 6 waves/SIMD -> 3 blocks/CU.
__global__ __launch_bounds__(512, 6) void conv_kernel(
    const float* __restrict__ x, const float* __restrict__ M,
    const float* __restrict__ bias, float* ws, short* __restrict__ pre)
{
    __shared__ int U[8704];
    __shared__ __align__(16) float Mlds[2176];
    __shared__ __align__(16) float offs[340];
    __shared__ float dlds[20];
    short (*A)[136] = (short(*)[136])U;     // phase 1 only

    const int tid = threadIdx.x;
    const int w = tid >> 6, l = tid & 63, c = l & 15, g = l >> 4;
    const int col = w * 16 + c;

    const float bv = bias[col];              // early; used in mixing

    for (int e = tid; e < 340; e += 512) offs[e] = ws[OFF_OFFSYM + e];
    if (tid < 17) dlds[tid] = ws[OFF_DIAG + tid];
    {   // stage M[17][128] -> LDS, 544 float4
        const float4* m4 = (const float4*)M;
        for (int e = tid; e < 544; e += 512)
            *(float4*)&Mlds[e * 4] = m4[e];
    }

    // ---- stage x[blk*68 .. +68) f32 -> bf16 LDS (2176 float4) ----
    const float4* xsrc = (const float4*)(x + (size_t)blockIdx.x * (68 * 128));
    #pragma unroll
    for (int it = 0; it < 5; ++it) {
        int f = tid + it * 512;
        if (f < 2176) {
            float4 v = xsrc[f];
            int r = f >> 5, k0 = (f & 31) << 2;
            pk4U p;
            p.u[0] = pk2(v.x, v.y);
            p.u[1] = pk2(v.z, v.w);
            *(bf16x4*)&A[r][k0] = p.v;
        }
    }
    __syncthreads();

    // ---- K-loop: wave w owns col for h0 (col) and h1 (col+128) ----
    const short* wbt = (const short*)(ws + OFF_WBT);
    f32x4 acc0[5], acc1[5];
    #pragma unroll
    for (int mt = 0; mt < 5; ++mt) {
        acc0[mt] = (f32x4){0.f, 0.f, 0.f, 0.f};
        acc1[mt] = (f32x4){0.f, 0.f, 0.f, 0.f};
    }
    #pragma unroll
    for (int ks = 0; ks < 4; ++ks) {
        bf16x8 b0 = *(const bf16x8*)(wbt + col * 128 + ks * 32 + g * 8);
        bf16x8 b1 = *(const bf16x8*)(wbt + (col + 128) * 128 + ks * 32 + g * 8);
        #pragma unroll
        for (int mt = 0; mt < 5; ++mt) {
            // mt=4 frag rows 68..79 don't exist: clamp (R6-proven); garbage
            // D-rows >=68 are discarded by the row<68 guard below.
            const int arow = (mt < 4) ? (mt * 16 + c) : (64 + (c & 3));
            bf16x8 af = *(const bf16x8*)&A[arow][ks * 32 + g * 8];
            acc0[mt] = __builtin_amdgcn_mfma_f32_16x16x32_bf16(af, b0, acc0[mt], 0, 0, 0);
            acc1[mt] = __builtin_amdgcn_mfma_f32_16x16x32_bf16(af, b1, acc1[mt], 0, 0, 0);
        }
    }
    __syncthreads();   // all waves' A reads done; U becomes per-wave hh slices

    // ---- epilogue (per-wave): pack acc via pure-C f2bf into own slice ----
    int* hw = U + w * 1088;                 // [68][16] ints
    #pragma unroll
    for (int mt = 0; mt < 5; ++mt) {
        #pragma unroll
        for (int r = 0; r < 4; ++r) {
            int row = mt * 16 + g * 4 + r;
            if (row < 68) {
                unsigned pk = ((unsigned)(unsigned short)f2bf(acc0[mt][r])) |
                              (((unsigned)(unsigned short)f2bf(acc1[mt][r])) << 16);
                hw[row * 16 + c] = (int)pk;
            }
        }
    }

    // ---- mixing (per-wave): lane (c,g) -> batch g, col; all inputs from LDS ----
    int pj[17]; float mcol[17];
    #pragma unroll
    for (int i = 0; i < 17; ++i) {
        pj[i]   = hw[(g * 17 + i) * 16 + c];
        mcol[i] = Mlds[i * 128 + col];
    }

    float vout[17];
    #pragma unroll
    for (int i = 0; i < 17; ++i)
        vout[i] = fmaf(dlds[i] * mcol[i], bflo(pj[i]), bv);   // diag*M*h0 + bias
    #pragma unroll
    for (int j = 0; j < 17; ++j) {
        float hv = mcol[j] * bfhi(pj[j]);                      // M*h1
        const f32x4* orow = (const f32x4*)&offs[j * 20];       // symmetric rows
        f32x4 o0 = orow[0], o1 = orow[1], o2 = orow[2], o3 = orow[3];
        float oz = offs[j * 20 + 16];
        vout[0]  = fmaf(o0.x, hv, vout[0]);
        vout[1]  = fmaf(o0.y, hv, vout[1]);
        vout[2]  = fmaf(o0.z, hv, vout[2]);
        vout[3]  = fmaf(o0.w, hv, vout[3]);
        vout[4]  = fmaf(o1.x, hv, vout[4]);
        vout[5]  = fmaf(o1.y, hv, vout[5]);
        vout[6]  = fmaf(o1.z, hv, vout[6]);
        vout[7]  = fmaf(o1.w, hv, vout[7]);
        vout[8]  = fmaf(o2.x, hv, vout[8]);
        vout[9]  = fmaf(o2.y, hv, vout[9]);
        vout[10] = fmaf(o2.z, hv, vout[10]);
        vout[11] = fmaf(o2.w, hv, vout[11]);
        vout[12] = fmaf(o3.x, hv, vout[12]);
        vout[13] = fmaf(o3.y, hv, vout[13]);
        vout[14] = fmaf(o3.z, hv, vout[14]);
        vout[15] = fmaf(o3.w, hv, vout[15]);
        vout[16] = fmaf(oz,   hv, vout[16]);
    }

    float s = 0.f, s2 = 0.f;
    const size_t gbase = ((size_t)blockIdx.x * 68 + g * 17) * 128 + col;
    #pragma unroll
    for (int i = 0; i < 17; ++i) {
        float v = vout[i];
        pre[gbase + (size_t)i * 128] = (short)pk2(v, v);   // v is VALU-produced: OK
        s += v; s2 = fmaf(v, v, s2);
    }

    // ---- stats: butterfly over g (lane bits 4,5), 16 lane-atomics/wave ----
    s  += __shfl_xor(s, 16);  s  += __shfl_xor(s, 32);
    s2 += __shfl_xor(s2, 16); s2 += __shfl_xor(s2, 32);
    if (l < 16) {
        float* slot = ws + OFF_PART + ((blockIdx.x & (NSLOT - 1)) << 8);
        atomicAdd(slot + col, s);
        atomicAdd(slot + 128 + col, s2);
    }
}

// ---------------- fallback fused conv (R11-proven, f32 out path) ----------------
__global__ __launch_bounds__(512, 4) void conv_f32_kernel(
    const float* __restrict__ x, const float* __restrict__ M,
    const float* __restrict__ bias, float* ws, float* __restrict__ out)
{
    __shared__ int hhI[68 * 130];
    __shared__ __align__(16) float offs[340];
    short (*A)[136] = (short(*)[136])hhI;
    const int tid = threadIdx.x;
    const int w = tid >> 6, l = tid & 63, c = l & 15, g = l >> 4;
    for (int e = tid; e < 340; e += 512) offs[e] = ws[OFF_OFFSYM + e];
    const float4* xsrc = (const float4*)(x + (size_t)blockIdx.x * (68 * 128));
    #pragma unroll
    for (int it = 0; it < 5; ++it) {
        int f = tid + it * 512;
        if (f < 2176) {
            float4 v = xsrc[f];
            int r = f >> 5, k0 = (f & 31) << 2;
            pk4U p; p.u[0] = pk2(v.x, v.y); p.u[1] = pk2(v.z, v.w);
            *(bf16x4*)&A[r][k0] = p.v;
        }
    }
    if (tid < 408) { bf16x4 z = {0,0,0,0}; ((bf16x4*)&A[68][0])[tid] = z; }
    __syncthreads();
    const short* wbt = (const short*)(ws + OFF_WBT);
    const int col = w * 16 + c;
    f32x4 acc0[5], acc1[5];
    #pragma unroll
    for (int mt = 0; mt < 5; ++mt) {
        acc0[mt] = (f32x4){0.f,0.f,0.f,0.f}; acc1[mt] = (f32x4){0.f,0.f,0.f,0.f};
    }
    #pragma unroll
    for (int ks = 0; ks < 4; ++ks) {
        bf16x8 b0 = *(const bf16x8*)(wbt + col * 128 + ks * 32 + g * 8);
        bf16x8 b1 = *(const bf16x8*)(wbt + (col + 128) * 128 + ks * 32 + g * 8);
        #pragma unroll
        for (int mt = 0; mt < 5; ++mt) {
            bf16x8 af = *(const bf16x8*)&A[mt * 16 + c][ks * 32 + g * 8];
            acc0[mt] = __builtin_amdgcn_mfma_f32_16x16x32_bf16(af, b0, acc0[mt], 0, 0, 0);
            acc1[mt] = __builtin_amdgcn_mfma_f32_16x16x32_bf16(af, b1, acc1[mt], 0, 0, 0);
        }
    }
    __syncthreads();
    const float bv = bias[col];
    #pragma unroll
    for (int mt = 0; mt < 5; ++mt) {
        #pragma unroll
        for (int r = 0; r < 4; ++r) {
            int row = mt * 16 + g * 4 + r;
            if (row < 68) {
                int j = row - 17 * ((row * 241) >> 12);
                float m  = M[j * 128 + col];
                float dg = ws[OFF_DIAG + j];
                float lo = fmaf(dg * m, acc0[mt][r], bv);
                float hi = m * acc1[mt][r];
                hhI[row * 130 + col] = (int)pk2(lo, hi);
            }
        }
    }
    __syncthreads();
    const int bb = tid >> 7, o = tid & 127;
    const int rb = bb * 17;
    int pj[17];
    #pragma unroll
    for (int i = 0; i < 17; ++i) pj[i] = hhI[(rb + i) * 130 + o];
    float vout[17];
    #pragma unroll
    for (int q = 0; q < 17; ++q) vout[q] = bflo(pj[q]);
    #pragma unroll
    for (int j = 0; j < 17; ++j) {
        float h1v = bfhi(pj[j]);
        #pragma unroll
        for (int q = 0; q < 17; ++q) vout[q] = fmaf(offs[j * 20 + q], h1v, vout[q]);
    }
    float s = 0.f, s2 = 0.f;
    const size_t gbase = ((size_t)blockIdx.x * 68 + rb) * 128 + o;
    #pragma unroll
    for (int q = 0; q < 17; ++q) {
        float v = vout[q];
        out[gbase + (size_t)q * 128] = v;
        s += v; s2 = fmaf(v, v, s2);
    }
    float* slot = ws + OFF_PART + ((blockIdx.x & (NSLOT - 1)) << 8);
    atomicAdd(slot + o, s);
    atomicAdd(slot + 128 + o, s2);
}

// ---------------- BN stats reduce ----------------
__global__ __launch_bounds__(256) void bn_reduce_kernel(
    const float* __restrict__ part, const float* __restrict__ gamma,
    const float* __restrict__ beta, float* __restrict__ stats)
{
    const int t = threadIdx.x;             // 0..255
    float s = 0.f;
    #pragma unroll 8
    for (int i = 0; i < NSLOT; ++i) s += part[i * 256 + t];
    __shared__ float tot[256];
    tot[t] = s;
    __syncthreads();
    if (t < 128) {
        const float n = 139264.f;          // 8192*17
        float mean = tot[t] / n;
        float var  = tot[t + 128] / n - mean * mean;
        var = fmaxf(var, 0.f);
        float inv = rsqrtf(var + 1e-5f);
        float sc = gamma[t] * inv;
        stats[t] = sc;
        stats[t + 128] = beta[t] - mean * sc;
    }
}

// ---------------- BN apply + relu: bf16 pre (ws) -> f32 out ----------------
__global__ __launch_bounds__(256) void apply_bf16_kernel(
    const short* __restrict__ pre, const float* __restrict__ stats,
    float* __restrict__ out)
{
    const int tid = blockIdx.x * 256 + threadIdx.x;
    const int c0 = (tid << 3) & 127;       // stride (524288*8) % 128 == 0
    float sc[8], sh[8];
    #pragma unroll
    for (int e = 0; e < 8; ++e) { sc[e] = stats[c0 + e]; sh[e] = stats[128 + c0 + e]; }
    const bf16x8* p8 = (const bf16x8*)pre;
    for (int q = tid; q < 2228224; q += 524288) {
        bf16x8 v = p8[q];
        float4 o0, o1;
        o0.x = fmaxf(fmaf(bf2f(v[0]), sc[0], sh[0]), 0.f);
        o0.y = fmaxf(fmaf(bf2f(v[1]), sc[1], sh[1]), 0.f);
        o0.z = fmaxf(fmaf(bf2f(v[2]), sc[2], sh[2]), 0.f);
        o0.w = fmaxf(fmaf(bf2f(v[3]), sc[3], sh[3]), 0.f);
        o1.x = fmaxf(fmaf(bf2f(v[4]), sc[4], sh[4]), 0.f);
        o1.y = fmaxf(fmaf(bf2f(v[5]), sc[5], sh[5]), 0.f);
        o1.z = fmaxf(fmaf(bf2f(v[6]), sc[6], sh[6]), 0.f);
        o1.w = fmaxf(fmaf(bf2f(v[7]), sc[7], sh[7]), 0.f);
        float4* dst = (float4*)(out + (size_t)q * 8);
        dst[0] = o0; dst[1] = o1;
    }
}

// ---------------- BN apply + relu fallback (in-place f32) ----------------
__global__ __launch_bounds__(256) void apply_kernel(
    float* __restrict__ out, const float* __restrict__ stats, int n4)
{
    const int tid = blockIdx.x * 256 + threadIdx.x;
    const int c0 = (tid << 2) & 127;
    const float sc0 = stats[c0],     sc1 = stats[c0 + 1],
                sc2 = stats[c0 + 2], sc3 = stats[c0 + 3];
    const float sh0 = stats[128 + c0],     sh1 = stats[128 + c0 + 1],
                sh2 = stats[128 + c0 + 2], sh3 = stats[128 + c0 + 3];
    float4* o4 = (float4*)out;
    for (int q = tid; q < n4; q += 2048 * 256) {
        float4 v = o4[q];
        v.x = fmaxf(fmaf(v.x, sc0, sh0), 0.f);
        v.y = fmaxf(fmaf(v.y, sc1, sh1), 0.f);
        v.z = fmaxf(fmaf(v.z, sc2, sh2), 0.f);
        v.w = fmaxf(fmaf(v.w, sc3, sh3), 0.f);
        o4[q] = v;
    }
}

extern "C" void kernel_launch(void* const* d_in, const int* in_sizes, int n_in,
                              void* d_out, int out_size, void* d_ws, size_t ws_size,
                              hipStream_t stream) {
    (void)in_sizes; (void)n_in; (void)out_size;
    const float* x     = (const float*)d_in[0];
    const float* W     = (const float*)d_in[1];
    const float* M     = (const float*)d_in[2];
    const float* adj   = (const float*)d_in[3];
    const float* adj2  = (const float*)d_in[4];
    const float* bias  = (const float*)d_in[5];
    const float* gamma = (const float*)d_in[6];
    const float* beta  = (const float*)d_in[7];
    float* out = (float*)d_out;
    float* wsf = (float*)d_ws;
    short* pre = (short*)(wsf + OFF_PRE);

    const bool big = ws_size >= (size_t)OFF_PRE * 4 + PRE_SHORTS * 2;

    (void)hipMemsetAsync(d_ws, 0, NSLOT * 256 * sizeof(float), stream);   // BN partials
    prep_kernel<<<17, 256, 0, stream>>>(W, adj, adj2, wsf);
    if (big) {
        conv_kernel<<<2048, 512, 0, stream>>>(x, M, bias, wsf, pre);
        bn_reduce_kernel<<<1, 256, 0, stream>>>(wsf + OFF_PART, gamma, beta, wsf + OFF_STATS);
        apply_bf16_kernel<<<2048, 256, 0, stream>>>(pre, wsf + OFF_STATS, out);
    } else {
        conv_f32_kernel<<<2048, 512, 0, stream>>>(x, M, bias, wsf, out);
        bn_reduce_kernel<<<1, 256, 0, stream>>>(wsf + OFF_PART, gamma, beta, wsf + OFF_STATS);
        apply_kernel<<<2048, 256, 0, stream>>>(out, wsf + OFF_STATS, 4456448);
    }
}